// Round 1
// baseline (1436.290 us; speedup 1.0000x reference)
//
#include <hip/hip_runtime.h>
#include <math.h>

#define N_SAMP 262144
#define HID 64
#define NW 4          // waves per block
#define BLK 256

// tanh via exp2-based fast exp; robust at extremes:
// x>>0: expf(2x)=inf -> 1-0 = 1;  x<<0: expf(2x)=0 -> 1-2 = -1.
__device__ __forceinline__ float fast_tanh(float x) {
    return 1.0f - 2.0f / (__expf(2.0f * x) + 1.0f);
}

struct SW {
    float W1[4096], W2[4096], W3[4096];
    float W0[192];
    float b0[64], b1[64], b2[64], b3[64];
    float W4[64];
    float b4;
};

__device__ __forceinline__ void load_weights(SW& sw,
    const float* W0, const float* b0, const float* W1, const float* b1,
    const float* W2, const float* b2, const float* W3, const float* b3,
    const float* W4, const float* b4)
{
    int tid = threadIdx.x;
    for (int i = tid; i < 4096; i += BLK) { sw.W1[i] = W1[i]; sw.W2[i] = W2[i]; sw.W3[i] = W3[i]; }
    for (int i = tid; i < 192; i += BLK) sw.W0[i] = W0[i];
    for (int i = tid; i < 64; i += BLK) {
        sw.b0[i] = b0[i]; sw.b1[i] = b1[i]; sw.b2[i] = b2[i]; sw.b3[i] = b3[i];
        sw.W4[i] = W4[i];
    }
    if (tid == 0) sw.b4 = b4[0];
}

// ---------------- data loss kernel: 6 samples per wave per iteration ----------------
__global__ __launch_bounds__(BLK) void data_kernel(
    const float* __restrict__ xd, const float* __restrict__ yd,
    const float* __restrict__ W0, const float* __restrict__ b0,
    const float* __restrict__ W1, const float* __restrict__ b1,
    const float* __restrict__ W2, const float* __restrict__ b2,
    const float* __restrict__ W3, const float* __restrict__ b3,
    const float* __restrict__ W4, const float* __restrict__ b4,
    double* __restrict__ acc)
{
    __shared__ SW sw;
    __shared__ __align__(16) float hb[NW][64][8];
    load_weights(sw, W0, b0, W1, b1, W2, b2, W3, b3, W4, b4);
    __syncthreads();

    const int wave = threadIdx.x >> 6;
    const int lane = threadIdx.x & 63;
    const int ngroups = (N_SAMP + 5) / 6;

    double acc_local = 0.0;
    const int step = gridDim.x * NW;
    for (int g0 = blockIdx.x * NW; g0 < ngroups; g0 += step) {
        const int g = g0 + wave;               // may exceed ngroups for trailing waves
        const int base = g * 6;
        float h[6];
        // layer 0: 3 -> 64, six independent samples as "channels"
        #pragma unroll
        for (int c = 0; c < 6; c++) {
            int s = base + c;
            bool act = (g < ngroups) && (s < N_SAMP);
            int sc = act ? s : 0;
            float x0 = xd[sc * 3 + 0], x1 = xd[sc * 3 + 1], x2 = xd[sc * 3 + 2];
            float z = sw.b0[lane] + x0 * sw.W0[lane] + x1 * sw.W0[64 + lane] + x2 * sw.W0[128 + lane];
            h[c] = fast_tanh(z);
        }
        // hidden layers 1..3
        const float* Wl;
        const float* bl;
        #pragma unroll
        for (int l = 0; l < 3; l++) {
            Wl = (l == 0) ? sw.W1 : (l == 1) ? sw.W2 : sw.W3;
            bl = (l == 0) ? sw.b1 : (l == 1) ? sw.b2 : sw.b3;
            __syncthreads();
            *(float4*)&hb[wave][lane][0] = make_float4(h[0], h[1], h[2], h[3]);
            *(float2*)&hb[wave][lane][4] = make_float2(h[4], h[5]);
            __syncthreads();
            float zb = bl[lane];
            float z[6] = { zb, zb, zb, zb, zb, zb };
            #pragma unroll 8
            for (int i = 0; i < 64; i++) {
                float w = Wl[i * 64 + lane];
                float4 p = *(const float4*)&hb[wave][i][0];
                float2 q = *(const float2*)&hb[wave][i][4];
                z[0] += w * p.x; z[1] += w * p.y; z[2] += w * p.z;
                z[3] += w * p.w; z[4] += w * q.x; z[5] += w * q.y;
            }
            #pragma unroll
            for (int c = 0; c < 6; c++) h[c] = fast_tanh(z[c]);
        }
        // final layer: 64 -> 1 for each of the 6 samples
        float t[6];
        float w4 = sw.W4[lane];
        #pragma unroll
        for (int c = 0; c < 6; c++) t[c] = w4 * h[c];
        #pragma unroll
        for (int m = 32; m > 0; m >>= 1) {
            #pragma unroll
            for (int c = 0; c < 6; c++) t[c] += __shfl_xor(t[c], m, 64);
        }
        if (lane == 0) {
            #pragma unroll
            for (int c = 0; c < 6; c++) {
                int s = base + c;
                if ((g < ngroups) && (s < N_SAMP)) {
                    float d = t[c] + sw.b4 - yd[s];
                    acc_local += (double)(d * d);
                }
            }
        }
    }
    if (lane == 0) atomicAdd(acc, acc_local);
}

// ---------------- PDE residual kernel: 1 sample per wave, 6 derivative channels ----------------
__global__ __launch_bounds__(BLK) void phys_kernel(
    const float* __restrict__ xp,
    const float* __restrict__ W0, const float* __restrict__ b0,
    const float* __restrict__ W1, const float* __restrict__ b1,
    const float* __restrict__ W2, const float* __restrict__ b2,
    const float* __restrict__ W3, const float* __restrict__ b3,
    const float* __restrict__ W4, const float* __restrict__ b4,
    const float* __restrict__ log_alpha,
    double* __restrict__ acc)
{
    __shared__ SW sw;
    __shared__ __align__(16) float hb[NW][64][8];
    load_weights(sw, W0, b0, W1, b1, W2, b2, W3, b3, W4, b4);
    __syncthreads();

    const int wave = threadIdx.x >> 6;
    const int lane = threadIdx.x & 63;
    const float alpha = __expf(log_alpha[0]);

    double acc_local = 0.0;
    const int step = gridDim.x * NW;
    for (int s0 = blockIdx.x * NW; s0 < N_SAMP; s0 += step) {
        const int s = s0 + wave;
        const bool active = s < N_SAMP;
        const int sc = active ? s : 0;
        float x0 = xp[sc * 3 + 0], x1 = xp[sc * 3 + 1], x2 = xp[sc * 3 + 2];

        // layer 0: 3 -> 64
        float w0r0 = sw.W0[lane], w0r1 = sw.W0[64 + lane], w0r2 = sw.W0[128 + lane];
        float z0 = sw.b0[lane] + x0 * w0r0 + x1 * w0r1 + x2 * w0r2;
        float a = fast_tanh(z0);
        float ap = 1.0f - a * a;
        float app = -2.0f * a * ap;
        // channels: 0=value 1=d/dx 2=d/dy 3=d/dt 4=d2/dx2 5=d2/dy2
        float h0 = a;
        float h1 = ap * w0r0;
        float h2 = ap * w0r1;
        float h3 = ap * w0r2;
        float h4 = app * w0r0 * w0r0;   // z_xx = 0 at layer 0
        float h5 = app * w0r1 * w0r1;

        // hidden layers 1..3
        #pragma unroll
        for (int l = 0; l < 3; l++) {
            const float* Wl = (l == 0) ? sw.W1 : (l == 1) ? sw.W2 : sw.W3;
            const float* bl = (l == 0) ? sw.b1 : (l == 1) ? sw.b2 : sw.b3;
            __syncthreads();
            *(float4*)&hb[wave][lane][0] = make_float4(h0, h1, h2, h3);
            *(float2*)&hb[wave][lane][4] = make_float2(h4, h5);
            __syncthreads();
            float z[6] = { bl[lane], 0.f, 0.f, 0.f, 0.f, 0.f };
            #pragma unroll 8
            for (int i = 0; i < 64; i++) {
                float w = Wl[i * 64 + lane];
                float4 p = *(const float4*)&hb[wave][i][0];
                float2 q = *(const float2*)&hb[wave][i][4];
                z[0] += w * p.x; z[1] += w * p.y; z[2] += w * p.z;
                z[3] += w * p.w; z[4] += w * q.x; z[5] += w * q.y;
            }
            a = fast_tanh(z[0]);
            ap = 1.0f - a * a;
            app = -2.0f * a * ap;
            h0 = a;
            h1 = ap * z[1];
            h2 = ap * z[2];
            h3 = ap * z[3];
            h4 = app * z[1] * z[1] + ap * z[4];
            h5 = app * z[2] * z[2] + ap * z[5];
        }

        // final linear layer: only need d/dt, d2/dx2, d2/dy2 outputs
        float w4 = sw.W4[lane];
        float t3 = w4 * h3, t4 = w4 * h4, t5 = w4 * h5;
        #pragma unroll
        for (int m = 32; m > 0; m >>= 1) {
            t3 += __shfl_xor(t3, m, 64);
            t4 += __shfl_xor(t4, m, 64);
            t5 += __shfl_xor(t5, m, 64);
        }
        if (lane == 0 && active) {
            float r = t3 - alpha * (t4 + t5);
            acc_local += (double)(r * r);
        }
    }
    if (lane == 0) atomicAdd(acc, acc_local);
}

__global__ void finalize_kernel(const double* __restrict__ acc,
                                const float* __restrict__ log_lambda,
                                const float* __restrict__ log_alpha,
                                float* __restrict__ out)
{
    float data_loss = (float)(acc[0] / (double)N_SAMP);
    float pde_loss  = (float)(acc[1] / (double)N_SAMP);
    float alpha = expf(log_alpha[0]);
    float lam   = expf(log_lambda[0]);
    out[0] = data_loss + lam * pde_loss;
    out[1] = data_loss;
    out[2] = pde_loss;
    out[3] = alpha;
    out[4] = lam;
}

extern "C" void kernel_launch(void* const* d_in, const int* in_sizes, int n_in,
                              void* d_out, int out_size, void* d_ws, size_t ws_size,
                              hipStream_t stream) {
    const float* xd = (const float*)d_in[0];
    const float* yd = (const float*)d_in[1];
    const float* xp = (const float*)d_in[2];
    const float* W0 = (const float*)d_in[3];
    const float* b0 = (const float*)d_in[4];
    const float* W1 = (const float*)d_in[5];
    const float* b1 = (const float*)d_in[6];
    const float* W2 = (const float*)d_in[7];
    const float* b2 = (const float*)d_in[8];
    const float* W3 = (const float*)d_in[9];
    const float* b3 = (const float*)d_in[10];
    const float* W4 = (const float*)d_in[11];
    const float* b4 = (const float*)d_in[12];
    const float* log_lambda = (const float*)d_in[13];
    const float* log_alpha  = (const float*)d_in[14];
    float* out = (float*)d_out;
    double* acc = (double*)d_ws;

    hipMemsetAsync(d_ws, 0, 2 * sizeof(double), stream);
    data_kernel<<<1024, BLK, 0, stream>>>(xd, yd, W0, b0, W1, b1, W2, b2, W3, b3, W4, b4, &acc[0]);
    phys_kernel<<<2048, BLK, 0, stream>>>(xp, W0, b0, W1, b1, W2, b2, W3, b3, W4, b4, log_alpha, &acc[1]);
    finalize_kernel<<<1, 1, 0, stream>>>(acc, log_lambda, log_alpha, out);
}

// Round 2
// 279.939 us; speedup vs baseline: 5.1307x; 5.1307x over previous
//
#include <hip/hip_runtime.h>
#include <math.h>

#define NSAMP 262144
#define NW 4
#define BLK 256
#define PB 436            // phys blocks
#define DB 76             // data blocks
#define GRID (PB + DB)    // 512 = 2 blocks/CU co-resident

typedef _Float16 f16x8 __attribute__((ext_vector_type(8)));
typedef _Float16 f16x4 __attribute__((ext_vector_type(4)));
typedef float    f32x4 __attribute__((ext_vector_type(4)));

__device__ __forceinline__ float fast_tanh(float x) {
    // robust at extremes: x>>0 -> 1, x<<0 -> -1
    return 1.0f - 2.0f / (__expf(2.0f * x) + 1.0f);
}

__device__ __forceinline__ double shfl_xor_d(double v, int m) {
    union { double d; int i[2]; } u; u.d = v;
    u.i[0] = __shfl_xor(u.i[0], m, 64);
    u.i[1] = __shfl_xor(u.i[1], m, 64);
    return u.d;
}

// Pointwise nonlinearity + channel mixing on C-layout fragments.
// acc[c][rt] holds z for rows rt*16 + q*4 + r, col n (fp32).
// DATA: all 6 channels are independent samples -> h = tanh(z).
// PHYS: ch 0=val 1=dx 2=dy 3=dt 4=dxx 5=dyy forward-mode propagation.
// LAST: leave h in acc (fp32) for epilogue; else pack fp16 and store to
// the wave-private Hf buffer in exact B-fragment order.
template<bool DATA, bool LAST>
__device__ __forceinline__ void pointwise_store(f32x4 acc[6][4], _Float16* sHf, int q, int n)
{
    #pragma unroll
    for (int rt = 0; rt < 4; rt++) {
        float hv[6][4];
        #pragma unroll
        for (int r = 0; r < 4; r++) {
            if (DATA) {
                #pragma unroll
                for (int c = 0; c < 6; c++) hv[c][r] = fast_tanh(acc[c][rt][r]);
            } else {
                float z0 = acc[0][rt][r], z1 = acc[1][rt][r], z2 = acc[2][rt][r];
                float z3 = acc[3][rt][r], z4 = acc[4][rt][r], z5 = acc[5][rt][r];
                float a   = fast_tanh(z0);
                float ap  = 1.0f - a * a;
                float app = -2.0f * a * ap;
                hv[0][r] = a;
                hv[1][r] = ap * z1;
                hv[2][r] = ap * z2;
                hv[3][r] = ap * z3;
                hv[4][r] = app * z1 * z1 + ap * z4;
                hv[5][r] = app * z2 * z2 + ap * z5;
            }
        }
        if (LAST) {
            #pragma unroll
            for (int c = 0; c < 6; c++)
                #pragma unroll
                for (int r = 0; r < 4; r++) acc[c][rt][r] = hv[c][r];
        } else {
            // row = rt*16 + q*4 + r  ->  k decomposition:
            // kt = row>>5 = rt>>1; kq = (row>>3)&3 = (2rt + (q>>1))&3; j = (q&1)*4 + r
            int ktd = rt >> 1;
            int qd  = (2 * rt + (q >> 1)) & 3;
            #pragma unroll
            for (int c = 0; c < 6; c++) {
                f16x4 p;
                p[0] = (_Float16)hv[c][0]; p[1] = (_Float16)hv[c][1];
                p[2] = (_Float16)hv[c][2]; p[3] = (_Float16)hv[c][3];
                *(f16x4*)&sHf[(((c * 2 + ktd) * 4 + qd) * 16 + n) * 8 + (q & 1) * 4] = p;
            }
        }
    }
}

template<bool DATA>
__device__ __forceinline__ double run_mode(
    const float* __restrict__ xd, const float* __restrict__ yd,
    const float* __restrict__ xp, float alpha,
    const _Float16* sWA, const _Float16* sWA0,
    const float (*sB)[64], const float* sW4, float b4,
    _Float16* sHf, int q, int n, int wstart, int wstride)
{
    f32x4 w4v[4];
    #pragma unroll
    for (int rt = 0; rt < 4; rt++)
        w4v[rt] = *(const f32x4*)&sW4[rt * 16 + q * 4];

    const f16x8 zf = {0, 0, 0, 0, 0, 0, 0, 0};
    const f32x4 z4v = {0.f, 0.f, 0.f, 0.f};
    double dacc = 0.0;
    const int NIT = DATA ? ((NSAMP + 95) / 96) : (NSAMP / 16);

    for (int it = wstart; it < NIT; it += wstride) {
        f32x4 acc[6][4];
        // ---------------- layer 0 (K=32 padded, only k<3 nonzero) ----------------
        f16x8 b0f[6];
        #pragma unroll
        for (int c = 0; c < 6; c++) b0f[c] = zf;
        if (DATA) {
            if (q == 0) {
                #pragma unroll
                for (int c = 0; c < 6; c++) {
                    int s = it * 96 + c * 16 + n;
                    if (s < NSAMP) {
                        b0f[c][0] = (_Float16)xd[s * 3 + 0];
                        b0f[c][1] = (_Float16)xd[s * 3 + 1];
                        b0f[c][2] = (_Float16)xd[s * 3 + 2];
                    }
                }
            }
        } else {
            if (q == 0) {
                int s = it * 16 + n;
                b0f[0][0] = (_Float16)xp[s * 3 + 0];
                b0f[0][1] = (_Float16)xp[s * 3 + 1];
                b0f[0][2] = (_Float16)xp[s * 3 + 2];
                b0f[1][0] = (_Float16)1.0f;   // d/dx seed
                b0f[2][1] = (_Float16)1.0f;   // d/dy seed
                b0f[3][2] = (_Float16)1.0f;   // d/dt seed
                // ch 4,5: z_xx = z_yy = 0 at layer 0
            }
        }
        #pragma unroll
        for (int rt = 0; rt < 4; rt++) {
            f32x4 bias4 = *(const f32x4*)&sB[0][rt * 16 + q * 4];
            #pragma unroll
            for (int c = 0; c < 6; c++)
                acc[c][rt] = (DATA || c == 0) ? bias4 : z4v;
        }
        #pragma unroll
        for (int rt = 0; rt < 4; rt++) {
            f16x8 a = (q == 0) ? *(const f16x8*)&sWA0[(rt * 16 + n) * 8] : zf;
            #pragma unroll
            for (int c = 0; c < 6; c++)
                acc[c][rt] = __builtin_amdgcn_mfma_f32_16x16x32_f16(a, b0f[c], acc[c][rt], 0, 0, 0);
        }
        pointwise_store<DATA, false>(acc, sHf, q, n);

        // ---------------- hidden layers 1..3 ----------------
        #pragma unroll
        for (int l = 0; l < 3; l++) {
            asm volatile("s_waitcnt lgkmcnt(0)" ::: "memory");
            f16x8 bf[6][2];
            #pragma unroll
            for (int c = 0; c < 6; c++)
                #pragma unroll
                for (int kt = 0; kt < 2; kt++)
                    bf[c][kt] = *(const f16x8*)&sHf[(((c * 2 + kt) * 4 + q) * 16 + n) * 8];
            #pragma unroll
            for (int rt = 0; rt < 4; rt++) {
                f32x4 bias4 = *(const f32x4*)&sB[l + 1][rt * 16 + q * 4];
                #pragma unroll
                for (int c = 0; c < 6; c++)
                    acc[c][rt] = (DATA || c == 0) ? bias4 : z4v;
            }
            #pragma unroll
            for (int kt = 0; kt < 2; kt++)
                #pragma unroll
                for (int rt = 0; rt < 4; rt++) {
                    f16x8 a = *(const f16x8*)&sWA[((((l * 4 + rt) * 2 + kt) * 4 + q) * 16 + n) * 8];
                    #pragma unroll
                    for (int c = 0; c < 6; c++)
                        acc[c][rt] = __builtin_amdgcn_mfma_f32_16x16x32_f16(a, bf[c][kt], acc[c][rt], 0, 0, 0);
                }
            if (l < 2) pointwise_store<DATA, false>(acc, sHf, q, n);
            else       pointwise_store<DATA, true >(acc, sHf, q, n);
        }

        // ---------------- epilogue: final 64->1 layer ----------------
        if (DATA) {
            float t[6];
            #pragma unroll
            for (int c = 0; c < 6; c++) {
                float s_ = 0.f;
                #pragma unroll
                for (int rt = 0; rt < 4; rt++)
                    #pragma unroll
                    for (int r = 0; r < 4; r++) s_ += w4v[rt][r] * acc[c][rt][r];
                s_ += __shfl_xor(s_, 16, 64);
                s_ += __shfl_xor(s_, 32, 64);
                t[c] = s_;
            }
            if (q == 0) {
                #pragma unroll
                for (int c = 0; c < 6; c++) {
                    int s = it * 96 + c * 16 + n;
                    if (s < NSAMP) {
                        float d = t[c] + b4 - yd[s];
                        dacc += (double)d * (double)d;
                    }
                }
            }
        } else {
            float t3 = 0.f, t4 = 0.f, t5 = 0.f;
            #pragma unroll
            for (int rt = 0; rt < 4; rt++)
                #pragma unroll
                for (int r = 0; r < 4; r++) {
                    float w = w4v[rt][r];
                    t3 += w * acc[3][rt][r];
                    t4 += w * acc[4][rt][r];
                    t5 += w * acc[5][rt][r];
                }
            t3 += __shfl_xor(t3, 16, 64); t3 += __shfl_xor(t3, 32, 64);
            t4 += __shfl_xor(t4, 16, 64); t4 += __shfl_xor(t4, 32, 64);
            t5 += __shfl_xor(t5, 16, 64); t5 += __shfl_xor(t5, 32, 64);
            if (q == 0) {
                float r_ = t3 - alpha * (t4 + t5);
                dacc += (double)r_ * (double)r_;
            }
        }
    }
    return dacc;
}

__global__ __launch_bounds__(BLK, 2) void fused_kernel(
    const float* __restrict__ xd, const float* __restrict__ yd, const float* __restrict__ xp,
    const float* __restrict__ W0, const float* __restrict__ b0,
    const float* __restrict__ W1, const float* __restrict__ b1,
    const float* __restrict__ W2, const float* __restrict__ b2,
    const float* __restrict__ W3, const float* __restrict__ b3,
    const float* __restrict__ W4, const float* __restrict__ b4,
    const float* __restrict__ log_alpha,
    double* __restrict__ accg)
{
    // A-fragment-ordered fp16 weights: [l][rt][kt][q][mlo][j]
    __shared__ __align__(16) _Float16 sWA[3 * 4 * 2 * 4 * 16 * 8];   // 24576 B
    __shared__ __align__(16) _Float16 sWA0[4 * 16 * 8];              // 1024 B (layer0, q=0 only)
    __shared__ __align__(16) _Float16 sHf[NW][6 * 2 * 4 * 16 * 8];   // 49152 B, per-wave
    __shared__ __align__(16) float sB[4][64];
    __shared__ __align__(16) float sW4s[64];
    __shared__ float sb4;

    const int tid = threadIdx.x;
    for (int idx = tid; idx < 3 * 4096; idx += BLK) {
        int l = idx >> 12, rem = idx & 4095, k = rem >> 6, m = rem & 63;
        const float* Ws = (l == 0) ? W1 : (l == 1) ? W2 : W3;  // [in=k][out=m], A[m][k] = W[k][m]
        int rt = m >> 4, mlo = m & 15, kt = k >> 5, qq = (k >> 3) & 3, j = k & 7;
        sWA[((((l * 4 + rt) * 2 + kt) * 4 + qq) * 16 + mlo) * 8 + j] = (_Float16)Ws[k * 64 + m];
    }
    for (int idx = tid; idx < 512; idx += BLK) {
        int j = idx & 7, nn = (idx >> 3) & 15, rt = idx >> 7;
        int m = rt * 16 + nn;
        sWA0[idx] = (j < 3) ? (_Float16)W0[j * 64 + m] : (_Float16)0.0f;
    }
    for (int i = tid; i < 64; i += BLK) {
        sB[0][i] = b0[i]; sB[1][i] = b1[i]; sB[2][i] = b2[i]; sB[3][i] = b3[i];
        sW4s[i] = W4[i];
    }
    if (tid == 0) sb4 = b4[0];
    __syncthreads();   // the only block-wide barrier

    const int wave = tid >> 6, lane = tid & 63;
    const int q = lane >> 4, n = lane & 15;
    const float alpha = __expf(log_alpha[0]);

    double dacc;
    if (blockIdx.x < PB) {
        int ws = blockIdx.x * NW + wave;
        dacc = run_mode<false>(xd, yd, xp, alpha, sWA, sWA0, sB, sW4s, sb4,
                               &sHf[wave][0], q, n, ws, PB * NW);
    } else {
        int ws = (blockIdx.x - PB) * NW + wave;
        dacc = run_mode<true>(xd, yd, xp, alpha, sWA, sWA0, sB, sW4s, sb4,
                              &sHf[wave][0], q, n, ws, DB * NW);
    }
    #pragma unroll
    for (int m = 1; m < 64; m <<= 1) dacc = dacc + shfl_xor_d(dacc, m);
    if (lane == 0) atomicAdd(&accg[(blockIdx.x < PB) ? 1 : 0], dacc);
}

__global__ void finalize_kernel(const double* __restrict__ acc,
                                const float* __restrict__ log_lambda,
                                const float* __restrict__ log_alpha,
                                float* __restrict__ out)
{
    float data_loss = (float)(acc[0] / (double)NSAMP);
    float pde_loss  = (float)(acc[1] / (double)NSAMP);
    float alpha = expf(log_alpha[0]);
    float lam   = expf(log_lambda[0]);
    out[0] = data_loss + lam * pde_loss;
    out[1] = data_loss;
    out[2] = pde_loss;
    out[3] = alpha;
    out[4] = lam;
}

extern "C" void kernel_launch(void* const* d_in, const int* in_sizes, int n_in,
                              void* d_out, int out_size, void* d_ws, size_t ws_size,
                              hipStream_t stream) {
    const float* xd = (const float*)d_in[0];
    const float* yd = (const float*)d_in[1];
    const float* xp = (const float*)d_in[2];
    const float* W0 = (const float*)d_in[3];
    const float* b0 = (const float*)d_in[4];
    const float* W1 = (const float*)d_in[5];
    const float* b1 = (const float*)d_in[6];
    const float* W2 = (const float*)d_in[7];
    const float* b2 = (const float*)d_in[8];
    const float* W3 = (const float*)d_in[9];
    const float* b3 = (const float*)d_in[10];
    const float* W4 = (const float*)d_in[11];
    const float* b4 = (const float*)d_in[12];
    const float* log_lambda = (const float*)d_in[13];
    const float* log_alpha  = (const float*)d_in[14];
    float* out = (float*)d_out;
    double* acc = (double*)d_ws;

    hipMemsetAsync(d_ws, 0, 2 * sizeof(double), stream);
    fused_kernel<<<GRID, BLK, 0, stream>>>(xd, yd, xp, W0, b0, W1, b1, W2, b2, W3, b3,
                                           W4, b4, log_alpha, acc);
    finalize_kernel<<<1, 1, 0, stream>>>(acc, log_lambda, log_alpha, out);
}

// Round 4
// 218.077 us; speedup vs baseline: 6.5862x; 1.2837x over previous
//
#include <hip/hip_runtime.h>
#include <math.h>

#define NSAMP 262144
#define NW 4
#define BLK 256
#define PB 436            // phys blocks
#define DB 76             // data blocks
#define GRID (PB + DB)    // 512 = 2 blocks/CU

typedef _Float16 f16x8 __attribute__((ext_vector_type(8)));
typedef _Float16 f16x4 __attribute__((ext_vector_type(4)));
typedef __fp16   fp16x2 __attribute__((ext_vector_type(2)));
typedef float    f32x4 __attribute__((ext_vector_type(4)));

__device__ __forceinline__ float fast_tanh(float x) {
    // robust at extremes: x>>0 -> 1-0=1 ; x<<0 -> 1-2= -1
    float e = __expf(2.0f * x);
    float r = __builtin_amdgcn_rcpf(e + 1.0f);   // v_rcp_f32, no slow fp32 divide
    return 1.0f - 2.0f * r;
}

__device__ __forceinline__ f16x4 pk4(float a, float b, float c, float d) {
    union { f16x4 v; fp16x2 h[2]; } u;
    u.h[0] = __builtin_amdgcn_cvt_pkrtz(a, b);
    u.h[1] = __builtin_amdgcn_cvt_pkrtz(c, d);
    return u.v;
}

__device__ __forceinline__ double shfl_xor_d(double v, int m) {
    union { double d; int i[2]; } u; u.d = v;
    u.i[0] = __shfl_xor(u.i[0], m, 64);
    u.i[1] = __shfl_xor(u.i[1], m, 64);
    return u.d;
}

// pointwise on one rt's acc[6] (C-layout rows rt*16+q*4+r, col n) + fp16 pack
// + store to wave-private B-fragment buffer. stbrt = precomputed elem offset.
template<bool DATA>
__device__ __forceinline__ void pw_store(const f32x4* acc, _Float16* sHf, int stbrt)
{
    float h[6][4];
    #pragma unroll
    for (int r = 0; r < 4; r++) {
        if (DATA) {
            #pragma unroll
            for (int c = 0; c < 6; c++) h[c][r] = fast_tanh(acc[c][r]);
        } else {
            float z1 = acc[1][r], z2 = acc[2][r];
            float a   = fast_tanh(acc[0][r]);
            float ap  = 1.0f - a * a;
            float app = -2.0f * a * ap;
            h[0][r] = a;
            h[1][r] = ap * z1;
            h[2][r] = ap * z2;
            h[3][r] = ap * acc[3][r];
            h[4][r] = app * z1 * z1 + ap * acc[4][r];
            h[5][r] = app * z2 * z2 + ap * acc[5][r];
        }
    }
    #pragma unroll
    for (int c = 0; c < 6; c++)
        *(f16x4*)&sHf[c * 1024 + stbrt] = pk4(h[c][0], h[c][1], h[c][2], h[c][3]);
}

template<bool DATA>
__device__ __forceinline__ double run_mode(
    const float* __restrict__ xd, const float* __restrict__ yd,
    const float* __restrict__ xp, float alpha,
    const _Float16* sWA, const _Float16* sWA0,
    const float (*sB)[64], const float* sW4, float b4,
    _Float16* sHf, int q, int n, int wstart, int wstride)
{
    const f16x8 zf = {0, 0, 0, 0, 0, 0, 0, 0};
    const f32x4 z4 = {0.f, 0.f, 0.f, 0.f};

    const int rdbase = q * 128 + n * 8;            // B-frag read base (elems)
    int stb[4];
    #pragma unroll
    for (int rt = 0; rt < 4; rt++)                 // C-row -> B-frag store offset
        stb[rt] = (rt >> 1) * 512 + (((2 * rt + (q >> 1)) & 3) * 128) + n * 8 + (q & 1) * 4;

    f32x4 w4v[4];
    #pragma unroll
    for (int rt = 0; rt < 4; rt++) w4v[rt] = *(const f32x4*)&sW4[rt * 16 + q * 4];

    const int NIT = DATA ? ((NSAMP + 95) / 96) : (NSAMP / 16);
    double dacc = 0.0;

    for (int it = wstart; it < NIT; it += wstride) {
        // ---------------- layer 0 (K=32 padded, k<3 nonzero) ----------------
        f16x8 b0f[6];
        #pragma unroll
        for (int c = 0; c < 6; c++) b0f[c] = zf;
        if (DATA) {
            if (q == 0) {
                #pragma unroll
                for (int c = 0; c < 6; c++) {
                    int s = it * 96 + c * 16 + n;
                    if (s < NSAMP) {
                        b0f[c][0] = (_Float16)xd[s * 3 + 0];
                        b0f[c][1] = (_Float16)xd[s * 3 + 1];
                        b0f[c][2] = (_Float16)xd[s * 3 + 2];
                    }
                }
            }
        } else {
            if (q == 0) {
                int s = it * 16 + n;
                b0f[0][0] = (_Float16)xp[s * 3 + 0];
                b0f[0][1] = (_Float16)xp[s * 3 + 1];
                b0f[0][2] = (_Float16)xp[s * 3 + 2];
                b0f[1][0] = (_Float16)1.0f;   // d/dx seed
                b0f[2][1] = (_Float16)1.0f;   // d/dy seed
                b0f[3][2] = (_Float16)1.0f;   // d/dt seed
            }
        }
        #pragma unroll
        for (int rt = 0; rt < 4; rt++) {
            f16x8 a0 = *(const f16x8*)&sWA0[(rt * 16 + n) * 8];
            a0 = (q == 0) ? a0 : zf;
            f32x4 bias = *(const f32x4*)&sB[0][rt * 16 + q * 4];
            f32x4 acc[6];
            if (DATA) {
                #pragma unroll
                for (int c = 0; c < 6; c++)
                    acc[c] = __builtin_amdgcn_mfma_f32_16x16x32_f16(a0, b0f[c], bias, 0, 0, 0);
            } else {
                acc[0] = __builtin_amdgcn_mfma_f32_16x16x32_f16(a0, b0f[0], bias, 0, 0, 0);
                #pragma unroll
                for (int c = 1; c < 4; c++)
                    acc[c] = __builtin_amdgcn_mfma_f32_16x16x32_f16(a0, b0f[c], z4, 0, 0, 0);
                acc[4] = z4; acc[5] = z4;   // z_xx = z_yy = 0 at layer 0
            }
            pw_store<DATA>(acc, sHf, stb[rt]);
        }

        // ---------------- hidden layers 1..3 ----------------
        float t[6] = {0.f, 0.f, 0.f, 0.f, 0.f, 0.f};   // DATA epilogue partials
        float t3 = 0.f, t4 = 0.f, t5 = 0.f;            // PHYS epilogue partials
        #pragma unroll
        for (int l = 0; l < 3; l++) {
            f16x8 bf[6][2];
            #pragma unroll
            for (int c = 0; c < 6; c++)
                #pragma unroll
                for (int kt = 0; kt < 2; kt++)
                    bf[c][kt] = *(const f16x8*)&sHf[c * 1024 + kt * 512 + rdbase];

            #pragma unroll
            for (int rt = 0; rt < 4; rt++) {
                f16x8 a0k = *(const f16x8*)&sWA[((((l * 4 + rt) * 2 + 0) * 4 + q) * 16 + n) * 8];
                f16x8 a1k = *(const f16x8*)&sWA[((((l * 4 + rt) * 2 + 1) * 4 + q) * 16 + n) * 8];
                f32x4 bias = *(const f32x4*)&sB[l + 1][rt * 16 + q * 4];
                f32x4 acc[6];
                #pragma unroll
                for (int c = 0; c < 6; c++) {
                    f32x4 cin = (DATA || c == 0) ? bias : z4;
                    acc[c] = __builtin_amdgcn_mfma_f32_16x16x32_f16(a0k, bf[c][0], cin, 0, 0, 0);
                    acc[c] = __builtin_amdgcn_mfma_f32_16x16x32_f16(a1k, bf[c][1], acc[c], 0, 0, 0);
                }
                if (l < 2) {
                    pw_store<DATA>(acc, sHf, stb[rt]);
                } else {
                    // LAST layer: fold final 64->1 dot into epilogue partials
                    #pragma unroll
                    for (int r = 0; r < 4; r++) {
                        float w = w4v[rt][r];
                        if (DATA) {
                            #pragma unroll
                            for (int c = 0; c < 6; c++) t[c] += w * fast_tanh(acc[c][r]);
                        } else {
                            float z1 = acc[1][r], z2 = acc[2][r];
                            float a   = fast_tanh(acc[0][r]);
                            float ap  = 1.0f - a * a;
                            float app = -2.0f * a * ap;
                            t3 += w * (ap * acc[3][r]);
                            t4 += w * (app * z1 * z1 + ap * acc[4][r]);
                            t5 += w * (app * z2 * z2 + ap * acc[5][r]);
                        }
                    }
                }
            }
        }

        // ---------------- epilogue ----------------
        if (DATA) {
            #pragma unroll
            for (int c = 0; c < 6; c++) {
                t[c] += __shfl_xor(t[c], 16, 64);
                t[c] += __shfl_xor(t[c], 32, 64);
            }
            if (q == 0) {
                #pragma unroll
                for (int c = 0; c < 6; c++) {
                    int s = it * 96 + c * 16 + n;
                    if (s < NSAMP) {
                        float d = t[c] + b4 - yd[s];
                        dacc += (double)d * (double)d;
                    }
                }
            }
        } else {
            t3 += __shfl_xor(t3, 16, 64); t3 += __shfl_xor(t3, 32, 64);
            t4 += __shfl_xor(t4, 16, 64); t4 += __shfl_xor(t4, 32, 64);
            t5 += __shfl_xor(t5, 16, 64); t5 += __shfl_xor(t5, 32, 64);
            if (q == 0) {
                float r_ = t3 - alpha * (t4 + t5);
                dacc += (double)r_ * (double)r_;
            }
        }
    }
    return dacc;
}

__global__ __launch_bounds__(BLK, 2) void fused_kernel(
    const float* __restrict__ xd, const float* __restrict__ yd, const float* __restrict__ xp,
    const float* __restrict__ W0, const float* __restrict__ b0,
    const float* __restrict__ W1, const float* __restrict__ b1,
    const float* __restrict__ W2, const float* __restrict__ b2,
    const float* __restrict__ W3, const float* __restrict__ b3,
    const float* __restrict__ W4, const float* __restrict__ b4,
    const float* __restrict__ log_alpha,
    double* __restrict__ accg)
{
    __shared__ __align__(16) _Float16 sWA[3 * 4 * 2 * 4 * 16 * 8];   // 24576 B
    __shared__ __align__(16) _Float16 sWA0[4 * 16 * 8];              // 1024 B
    __shared__ __align__(16) _Float16 sHf[NW][6 * 2 * 4 * 16 * 8];   // 49152 B, per-wave
    __shared__ __align__(16) float sB[4][64];
    __shared__ __align__(16) float sW4s[64];
    __shared__ float sb4;

    const int tid = threadIdx.x;
    for (int idx = tid; idx < 3 * 4096; idx += BLK) {
        int l = idx >> 12, rem = idx & 4095, k = rem >> 6, m = rem & 63;
        const float* Ws = (l == 0) ? W1 : (l == 1) ? W2 : W3;  // [in=k][out=m]; A[m][k]=W[k][m]
        int rt = m >> 4, mlo = m & 15, kt = k >> 5, qq = (k >> 3) & 3, j = k & 7;
        sWA[((((l * 4 + rt) * 2 + kt) * 4 + qq) * 16 + mlo) * 8 + j] = (_Float16)Ws[k * 64 + m];
    }
    for (int idx = tid; idx < 512; idx += BLK) {
        int j = idx & 7, nn = (idx >> 3) & 15, rt = idx >> 7;
        int m = rt * 16 + nn;
        sWA0[idx] = (j < 3) ? (_Float16)W0[j * 64 + m] : (_Float16)0.0f;
    }
    for (int i = tid; i < 64; i += BLK) {
        sB[0][i] = b0[i]; sB[1][i] = b1[i]; sB[2][i] = b2[i]; sB[3][i] = b3[i];
        sW4s[i] = W4[i];
    }
    if (tid == 0) sb4 = b4[0];
    __syncthreads();   // only block-wide barrier

    const int wave = tid >> 6, lane = tid & 63;
    const int q = lane >> 4, n = lane & 15;
    const float alpha = __expf(log_alpha[0]);

    double dacc;
    if (blockIdx.x < PB) {
        int ws = blockIdx.x * NW + wave;
        dacc = run_mode<false>(xd, yd, xp, alpha, sWA, sWA0, sB, sW4s, sb4,
                               &sHf[wave][0], q, n, ws, PB * NW);
    } else {
        int ws = (blockIdx.x - PB) * NW + wave;
        dacc = run_mode<true>(xd, yd, xp, alpha, sWA, sWA0, sB, sW4s, sb4,
                              &sHf[wave][0], q, n, ws, DB * NW);
    }
    #pragma unroll
    for (int m = 1; m < 64; m <<= 1) dacc = dacc + shfl_xor_d(dacc, m);
    if (lane == 0) atomicAdd(&accg[(blockIdx.x < PB) ? 1 : 0], dacc);
}

__global__ void finalize_kernel(const double* __restrict__ acc,
                                const float* __restrict__ log_lambda,
                                const float* __restrict__ log_alpha,
                                float* __restrict__ out)
{
    float data_loss = (float)(acc[0] / (double)NSAMP);
    float pde_loss  = (float)(acc[1] / (double)NSAMP);
    float alpha = expf(log_alpha[0]);
    float lam   = expf(log_lambda[0]);
    out[0] = data_loss + lam * pde_loss;
    out[1] = data_loss;
    out[2] = pde_loss;
    out[3] = alpha;
    out[4] = lam;
}

extern "C" void kernel_launch(void* const* d_in, const int* in_sizes, int n_in,
                              void* d_out, int out_size, void* d_ws, size_t ws_size,
                              hipStream_t stream) {
    const float* xd = (const float*)d_in[0];
    const float* yd = (const float*)d_in[1];
    const float* xp = (const float*)d_in[2];
    const float* W0 = (const float*)d_in[3];
    const float* b0 = (const float*)d_in[4];
    const float* W1 = (const float*)d_in[5];
    const float* b1 = (const float*)d_in[6];
    const float* W2 = (const float*)d_in[7];
    const float* b2 = (const float*)d_in[8];
    const float* W3 = (const float*)d_in[9];
    const float* b3 = (const float*)d_in[10];
    const float* W4 = (const float*)d_in[11];
    const float* b4 = (const float*)d_in[12];
    const float* log_lambda = (const float*)d_in[13];
    const float* log_alpha  = (const float*)d_in[14];
    float* out = (float*)d_out;
    double* acc = (double*)d_ws;

    (void)hipMemsetAsync(d_ws, 0, 2 * sizeof(double), stream);
    fused_kernel<<<GRID, BLK, 0, stream>>>(xd, yd, xp, W0, b0, W1, b1, W2, b2, W3, b3,
                                           W4, b4, log_alpha, acc);
    finalize_kernel<<<1, 1, 0, stream>>>(acc, log_lambda, log_alpha, out);
}